// Round 16
// baseline (71.310 us; speedup 1.0000x reference)
//
#include <hip/hip_runtime.h>
#include <math.h>

#define NN 8192
#define NEMBD 128
#define NHID 64
#define NCLS 16
#define MAXN 256
#define NEG_SLOPE 0.2f

typedef float f4 __attribute__((ext_vector_type(4)));

__device__ __forceinline__ float wave_sum64(float v) {
    v += __shfl_xor(v, 1);
    v += __shfl_xor(v, 2);
    v += __shfl_xor(v, 4);
    v += __shfl_xor(v, 8);
    v += __shfl_xor(v, 16);
    v += __shfl_xor(v, 32);
    return v;
}

// K1: adj-row scan, software-pipelined 1 chunk (4KB) deep, h1 = x@W1
// interleaved. wave per row, 2048 blocks. PLAIN adj loads (settled r13/r14).
// NEW: row forced wave-uniform via readfirstlane -> x loads become s_loads
// (lgkmcnt path, not vmcnt) -> no xv staging, 16 fewer VMEM ops/chunk,
// -16 VGPR. W1 vector loads still staged before the adj prefetch.
__global__ __launch_bounds__(256) void k1_scan_h1(
    const float* __restrict__ adj, const float* __restrict__ x,
    const float* __restrict__ W1,
    const float* __restrict__ a1s, const float* __restrict__ a1d,
    float* __restrict__ h1, float* __restrict__ als, float* __restrict__ ald,
    int* __restrict__ g_cnt, int* __restrict__ g_nbr) {
    __shared__ int s_idx[4][MAXN];
    int wid = threadIdx.x >> 6, lane = threadIdx.x & 63;
    int row = __builtin_amdgcn_readfirstlane(blockIdx.x * 4 + wid);
    const f4* arow = (const f4*)(adj + (size_t)row * NN);
    const float* xr = x + (size_t)row * NEMBD;   // uniform base -> s_loads
    unsigned long long lt = (1ull << lane) - 1ull;
    int base = 0;
    float hacc = 0.f;

    f4 cur0 = arow[0 * 64 + lane];
    f4 cur1 = arow[1 * 64 + lane];
    f4 cur2 = arow[2 * 64 + lane];
    f4 cur3 = arow[3 * 64 + lane];

#pragma unroll 1
    for (int c = 0; c < 8; ++c) {
        // stage W1 (vector loads, oldest on vmcnt after cur)
        float w1v[16];
#pragma unroll
        for (int j = 0; j < 16; ++j)
            w1v[j] = W1[(c * 16 + j) * NHID + lane];
        // prefetch next adj chunk (young vmcnt entries, stay in flight)
        f4 nxt0 = {0,0,0,0}, nxt1 = {0,0,0,0}, nxt2 = {0,0,0,0}, nxt3 = {0,0,0,0};
        if (c < 7) {
            const f4* p = arow + (c + 1) * 256 + lane;
            nxt0 = p[0 * 64];
            nxt1 = p[1 * 64];
            nxt2 = p[2 * 64];
            nxt3 = p[3 * 64];
        }
        // h1 FMAs: x via s_load (lgkmcnt), W1 via staged regs (vmcnt(4))
#pragma unroll
        for (int j = 0; j < 16; ++j)
            hacc = fmaf(xr[c * 16 + j], w1v[j], hacc);
#pragma unroll
        for (int j = 0; j < 4; ++j) {
            f4 v = (j == 0) ? cur0 : (j == 1) ? cur1 : (j == 2) ? cur2 : cur3;
            int it = c * 4 + j;
#pragma unroll
            for (int s = 0; s < 4; ++s) {
                bool nz = v[s] > 0.f;
                unsigned long long m = __ballot(nz);
                if (m != 0ull) {
                    if (nz) {
                        int pos = base + __popcll(m & lt);
                        s_idx[wid][pos] = it * 256 + lane * 4 + s;
                    }
                    base += __popcll(m);
                }
            }
        }
        cur0 = nxt0; cur1 = nxt1; cur2 = nxt2; cur3 = nxt3;
    }

    int cnt = base < MAXN ? base : MAXN;
    if (lane == 0) g_cnt[row] = cnt;
    for (int n = lane; n < cnt; n += 64)
        g_nbr[(size_t)row * MAXN + n] = s_idx[wid][n];
    h1[(size_t)row * NHID + lane] = hacc;
    float ts = wave_sum64(hacc * a1s[lane]);
    float td = wave_sum64(hacc * a1d[lane]);
    if (lane == 0) { als[row] = ts; ald[row] = td; }
}

// K2: SINGLE-PASS attn-1 (no max-shift: |e|<~15, exp safe in fp32) +
// batched gather + ELU + h2 = .@W2 + alphas2. lane = (c4 0..15, kk 0..3).
// row uniform via readfirstlane (scalar als/g_cnt reads). No block barrier.
__global__ __launch_bounds__(256) void k2_attn1_h2(
    const float* __restrict__ h1, const float* __restrict__ als,
    const float* __restrict__ ald, const float* __restrict__ b1,
    const float* __restrict__ W2, const float* __restrict__ a2s,
    const float* __restrict__ a2d,
    const int* __restrict__ g_cnt, const int* __restrict__ g_nbr,
    float* __restrict__ h2, float* __restrict__ als2, float* __restrict__ ald2) {
    __shared__ int   s_idx[4][MAXN];
    __shared__ float s_h[4][NHID];
    int wid = threadIdx.x >> 6, lane = threadIdx.x & 63;
    int row = __builtin_amdgcn_readfirstlane(blockIdx.x * 4 + wid);
    int cnt = g_cnt[row];
    for (int n = lane; n < cnt; n += 64) s_idx[wid][n] = g_nbr[(size_t)row * MAXN + n];

    float asr = als[row];
    int c4 = lane & 15, kk = lane >> 4;
    f4 acc = {0.f, 0.f, 0.f, 0.f};
    float ssum = 0.f;
    int n = kk;
    for (; n + 28 < cnt; n += 32) {
        int j0 = s_idx[wid][n+0],  j1 = s_idx[wid][n+4],  j2 = s_idx[wid][n+8],  j3 = s_idx[wid][n+12];
        int j4 = s_idx[wid][n+16], j5 = s_idx[wid][n+20], j6 = s_idx[wid][n+24], j7 = s_idx[wid][n+28];
        float e0 = ald[j0], e1 = ald[j1], e2 = ald[j2], e3 = ald[j3];
        float e4 = ald[j4], e5 = ald[j5], e6 = ald[j6], e7 = ald[j7];
        f4 v0 = ((const f4*)(h1 + (size_t)j0 * NHID))[c4];
        f4 v1 = ((const f4*)(h1 + (size_t)j1 * NHID))[c4];
        f4 v2 = ((const f4*)(h1 + (size_t)j2 * NHID))[c4];
        f4 v3 = ((const f4*)(h1 + (size_t)j3 * NHID))[c4];
        f4 v4 = ((const f4*)(h1 + (size_t)j4 * NHID))[c4];
        f4 v5 = ((const f4*)(h1 + (size_t)j5 * NHID))[c4];
        f4 v6 = ((const f4*)(h1 + (size_t)j6 * NHID))[c4];
        f4 v7 = ((const f4*)(h1 + (size_t)j7 * NHID))[c4];
        float p0, p1, p2, p3, p4, p5, p6, p7;
        e0 += asr; e0 = e0 > 0.f ? e0 : NEG_SLOPE * e0; p0 = __expf(e0);
        e1 += asr; e1 = e1 > 0.f ? e1 : NEG_SLOPE * e1; p1 = __expf(e1);
        e2 += asr; e2 = e2 > 0.f ? e2 : NEG_SLOPE * e2; p2 = __expf(e2);
        e3 += asr; e3 = e3 > 0.f ? e3 : NEG_SLOPE * e3; p3 = __expf(e3);
        e4 += asr; e4 = e4 > 0.f ? e4 : NEG_SLOPE * e4; p4 = __expf(e4);
        e5 += asr; e5 = e5 > 0.f ? e5 : NEG_SLOPE * e5; p5 = __expf(e5);
        e6 += asr; e6 = e6 > 0.f ? e6 : NEG_SLOPE * e6; p6 = __expf(e6);
        e7 += asr; e7 = e7 > 0.f ? e7 : NEG_SLOPE * e7; p7 = __expf(e7);
        ssum += ((p0 + p1) + (p2 + p3)) + ((p4 + p5) + (p6 + p7));
#pragma unroll
        for (int u = 0; u < 4; ++u) {
            acc[u] = fmaf(p0, v0[u], acc[u]); acc[u] = fmaf(p1, v1[u], acc[u]);
            acc[u] = fmaf(p2, v2[u], acc[u]); acc[u] = fmaf(p3, v3[u], acc[u]);
            acc[u] = fmaf(p4, v4[u], acc[u]); acc[u] = fmaf(p5, v5[u], acc[u]);
            acc[u] = fmaf(p6, v6[u], acc[u]); acc[u] = fmaf(p7, v7[u], acc[u]);
        }
    }
    for (; n < cnt; n += 4) {
        int j = s_idx[wid][n];
        float e = asr + ald[j];
        e = e > 0.f ? e : NEG_SLOPE * e;
        float p = __expf(e);
        f4 v = ((const f4*)(h1 + (size_t)j * NHID))[c4];
        ssum += p;
        acc.x = fmaf(p, v.x, acc.x);
        acc.y = fmaf(p, v.y, acc.y);
        acc.z = fmaf(p, v.z, acc.z);
        acc.w = fmaf(p, v.w, acc.w);
    }
    ssum += __shfl_xor(ssum, 16);
    ssum += __shfl_xor(ssum, 32);
    acc.x += __shfl_xor(acc.x, 16); acc.y += __shfl_xor(acc.y, 16);
    acc.z += __shfl_xor(acc.z, 16); acc.w += __shfl_xor(acc.w, 16);
    acc.x += __shfl_xor(acc.x, 32); acc.y += __shfl_xor(acc.y, 32);
    acc.z += __shfl_xor(acc.z, 32); acc.w += __shfl_xor(acc.w, 32);
    float rinv = 1.f / ssum;
    if (kk == 0) {
        f4 o;
#pragma unroll
        for (int j = 0; j < 4; ++j) {
            float t = acc[j] * rinv + b1[c4 * 4 + j];
            o[j] = t > 0.f ? t : expm1f(t);
        }
        ((f4*)s_h[wid])[c4] = o;
    }
    // same-wave LDS handoff: no s_barrier needed (lgkmcnt ordering)

    int c = lane & 15, k = lane >> 4;
    float a2 = 0.f;
#pragma unroll
    for (int f = k * 16; f < k * 16 + 16; ++f)
        a2 = fmaf(s_h[wid][f], W2[f * NCLS + c], a2);
    a2 += __shfl_xor(a2, 16);
    a2 += __shfl_xor(a2, 32);
    if (lane < 16) h2[(size_t)row * NCLS + lane] = a2;
    float ts = a2 * a2s[c], td = a2 * a2d[c];
    ts += __shfl_xor(ts, 1); td += __shfl_xor(td, 1);
    ts += __shfl_xor(ts, 2); td += __shfl_xor(td, 2);
    ts += __shfl_xor(ts, 4); td += __shfl_xor(td, 4);
    ts += __shfl_xor(ts, 8); td += __shfl_xor(td, 8);
    if (lane == 0) { als2[row] = ts; ald2[row] = td; }
}

// K3: SINGLE-PASS layer-2 GAT. lane = (c4 0..3, kk 0..15); merge over d=4..32.
__global__ __launch_bounds__(256) void k3_attn2(
    const float* __restrict__ h2, const float* __restrict__ als2,
    const float* __restrict__ ald2, const float* __restrict__ b2,
    const int* __restrict__ g_cnt, const int* __restrict__ g_nbr,
    float* __restrict__ out) {
    __shared__ int s_idx[4][MAXN];
    int wid = threadIdx.x >> 6, lane = threadIdx.x & 63;
    int row = __builtin_amdgcn_readfirstlane(blockIdx.x * 4 + wid);
    int cnt = g_cnt[row];
    for (int n = lane; n < cnt; n += 64) s_idx[wid][n] = g_nbr[(size_t)row * MAXN + n];

    float asr = als2[row];
    int c4 = lane & 3, kk = lane >> 2;
    f4 acc = {0.f, 0.f, 0.f, 0.f};
    float ssum = 0.f;
#pragma unroll 2
    for (int n = kk; n < cnt; n += 16) {
        int j = s_idx[wid][n];
        float e = asr + ald2[j];
        e = e > 0.f ? e : NEG_SLOPE * e;
        float p = __expf(e);
        f4 v = ((const f4*)(h2 + (size_t)j * NCLS))[c4];
        ssum += p;
        acc.x = fmaf(p, v.x, acc.x);
        acc.y = fmaf(p, v.y, acc.y);
        acc.z = fmaf(p, v.z, acc.z);
        acc.w = fmaf(p, v.w, acc.w);
    }
#pragma unroll
    for (int d = 4; d <= 32; d <<= 1) {
        ssum  += __shfl_xor(ssum, d);
        acc.x += __shfl_xor(acc.x, d); acc.y += __shfl_xor(acc.y, d);
        acc.z += __shfl_xor(acc.z, d); acc.w += __shfl_xor(acc.w, d);
    }
    if (kk == 0) {
        float rinv = 1.f / ssum;
        f4 o;
#pragma unroll
        for (int j = 0; j < 4; ++j) {
            float t = acc[j] * rinv + b2[c4 * 4 + j];
            o[j] = t > 0.f ? t : expm1f(t);
        }
        ((f4*)(out + (size_t)row * NCLS))[c4] = o;
    }
}

extern "C" void kernel_launch(void* const* d_in, const int* in_sizes, int n_in,
                              void* d_out, int out_size, void* d_ws, size_t ws_size,
                              hipStream_t stream) {
    const float* x   = (const float*)d_in[0];
    const float* adj = (const float*)d_in[1];
    const float* W1  = (const float*)d_in[2];
    const float* a1s = (const float*)d_in[3];
    const float* a1d = (const float*)d_in[4];
    const float* b1  = (const float*)d_in[5];
    const float* W2  = (const float*)d_in[6];
    const float* a2s = (const float*)d_in[7];
    const float* a2d = (const float*)d_in[8];
    const float* b2  = (const float*)d_in[9];
    float* out = (float*)d_out;

    char* ws = (char*)d_ws;
    float* h1   = (float*)(ws + 0);          // 2,097,152
    float* h2v  = (float*)(ws + 2097152);    // 524,288
    float* als1 = (float*)(ws + 2621440);
    float* ald1 = (float*)(ws + 2654208);
    float* als2 = (float*)(ws + 2686976);
    float* ald2 = (float*)(ws + 2719744);
    int*   gcnt = (int*)  (ws + 2752512);
    int*   gnbr = (int*)  (ws + 2785280);    // 8,388,608

    dim3 blk(256);
    dim3 grid(NN / 4);
    k1_scan_h1 <<<grid, blk, 0, stream>>>(adj, x, W1, a1s, a1d, h1, als1, ald1, gcnt, gnbr);
    k2_attn1_h2<<<grid, blk, 0, stream>>>(h1, als1, ald1, b1, W2, a2s, a2d, gcnt, gnbr,
                                          h2v, als2, ald2);
    k3_attn2   <<<grid, blk, 0, stream>>>(h2v, als2, ald2, b2, gcnt, gnbr, out);
}

// Round 17
// 70.405 us; speedup vs baseline: 1.0128x; 1.0128x over previous
//
#include <hip/hip_runtime.h>
#include <math.h>

#define NN 8192
#define NEMBD 128
#define NHID 64
#define NCLS 16
#define MAXN 256
#define NEG_SLOPE 0.2f

typedef float f4 __attribute__((ext_vector_type(4)));

__device__ __forceinline__ float wave_sum64(float v) {
    v += __shfl_xor(v, 1);
    v += __shfl_xor(v, 2);
    v += __shfl_xor(v, 4);
    v += __shfl_xor(v, 8);
    v += __shfl_xor(v, 16);
    v += __shfl_xor(v, 32);
    return v;
}

// K1: adj-row scan + h1 = x@W1 interleaved. wave per row, 2048 blocks.
// VGPR-TIER RESTRUCTURE: 2KB chunks (2xf4 live + 2xf4 prefetch) + w1v[8]
// + x via wave-uniform s_load -> live set < 64 VGPR -> 8 waves/SIMD
// (32 waves/CU) naturally, no spills (unlike r10's forced cap).
// PLAIN adj loads (settled r13/r14: plain beats nontemporal by ~6.5us).
__global__ __launch_bounds__(256) void k1_scan_h1(
    const float* __restrict__ adj, const float* __restrict__ x,
    const float* __restrict__ W1,
    const float* __restrict__ a1s, const float* __restrict__ a1d,
    float* __restrict__ h1, float* __restrict__ als, float* __restrict__ ald,
    int* __restrict__ g_cnt, int* __restrict__ g_nbr) {
    __shared__ int s_idx[4][MAXN];
    int wid = threadIdx.x >> 6, lane = threadIdx.x & 63;
    int row = __builtin_amdgcn_readfirstlane(blockIdx.x * 4 + wid);
    const f4* arow = (const f4*)(adj + (size_t)row * NN);
    const float* xr = x + (size_t)row * NEMBD;   // uniform base -> s_loads
    unsigned long long lt = (1ull << lane) - 1ull;
    int base = 0;
    float hacc = 0.f;

    f4 cur0 = arow[lane];
    f4 cur1 = arow[64 + lane];

#pragma unroll 1
    for (int c = 0; c < 16; ++c) {
        // stage W1 for this chunk's 8 k-steps (oldest vmcnt entries after cur)
        float w1v[8];
#pragma unroll
        for (int j = 0; j < 8; ++j)
            w1v[j] = W1[(c * 8 + j) * NHID + lane];
        // prefetch next 2KB chunk (young vmcnt entries, stay in flight)
        f4 n0 = {0,0,0,0}, n1 = {0,0,0,0};
        if (c < 15) {
            const f4* p = arow + (c + 1) * 128 + lane;
            n0 = p[0];
            n1 = p[64];
        }
        // h1 FMAs: x via s_load (lgkmcnt), W1 via staged regs
#pragma unroll
        for (int j = 0; j < 8; ++j)
            hacc = fmaf(xr[c * 8 + j], w1v[j], hacc);
        // ballots on current chunk
#pragma unroll
        for (int j = 0; j < 2; ++j) {
            f4 v = (j == 0) ? cur0 : cur1;
            int it = c * 2 + j;
#pragma unroll
            for (int s = 0; s < 4; ++s) {
                bool nz = v[s] > 0.f;
                unsigned long long m = __ballot(nz);
                if (m != 0ull) {           // wave-uniform skip (~53%)
                    if (nz) {
                        int pos = base + __popcll(m & lt);
                        s_idx[wid][pos] = it * 256 + lane * 4 + s;
                    }
                    base += __popcll(m);
                }
            }
        }
        cur0 = n0; cur1 = n1;
    }

    int cnt = base < MAXN ? base : MAXN;
    if (lane == 0) g_cnt[row] = cnt;
    for (int n = lane; n < cnt; n += 64)
        g_nbr[(size_t)row * MAXN + n] = s_idx[wid][n];
    h1[(size_t)row * NHID + lane] = hacc;
    float ts = wave_sum64(hacc * a1s[lane]);
    float td = wave_sum64(hacc * a1d[lane]);
    if (lane == 0) { als[row] = ts; ald[row] = td; }
}

// K2: SINGLE-PASS attn-1 (no max-shift: |e|<~15, exp safe in fp32) +
// batched gather + ELU + h2 = .@W2 + alphas2. lane = (c4 0..15, kk 0..3).
// NO block barrier: s_h[wid] is same-wave-only (compiler orders via lgkmcnt).
__global__ __launch_bounds__(256) void k2_attn1_h2(
    const float* __restrict__ h1, const float* __restrict__ als,
    const float* __restrict__ ald, const float* __restrict__ b1,
    const float* __restrict__ W2, const float* __restrict__ a2s,
    const float* __restrict__ a2d,
    const int* __restrict__ g_cnt, const int* __restrict__ g_nbr,
    float* __restrict__ h2, float* __restrict__ als2, float* __restrict__ ald2) {
    __shared__ int   s_idx[4][MAXN];
    __shared__ float s_h[4][NHID];
    int wid = threadIdx.x >> 6, lane = threadIdx.x & 63;
    int row = blockIdx.x * 4 + wid;
    int cnt = g_cnt[row];
    for (int n = lane; n < cnt; n += 64) s_idx[wid][n] = g_nbr[(size_t)row * MAXN + n];

    float asr = als[row];
    int c4 = lane & 15, kk = lane >> 4;
    f4 acc = {0.f, 0.f, 0.f, 0.f};
    float ssum = 0.f;
    int n = kk;
    for (; n + 28 < cnt; n += 32) {
        int j0 = s_idx[wid][n+0],  j1 = s_idx[wid][n+4],  j2 = s_idx[wid][n+8],  j3 = s_idx[wid][n+12];
        int j4 = s_idx[wid][n+16], j5 = s_idx[wid][n+20], j6 = s_idx[wid][n+24], j7 = s_idx[wid][n+28];
        float e0 = ald[j0], e1 = ald[j1], e2 = ald[j2], e3 = ald[j3];
        float e4 = ald[j4], e5 = ald[j5], e6 = ald[j6], e7 = ald[j7];
        f4 v0 = ((const f4*)(h1 + (size_t)j0 * NHID))[c4];
        f4 v1 = ((const f4*)(h1 + (size_t)j1 * NHID))[c4];
        f4 v2 = ((const f4*)(h1 + (size_t)j2 * NHID))[c4];
        f4 v3 = ((const f4*)(h1 + (size_t)j3 * NHID))[c4];
        f4 v4 = ((const f4*)(h1 + (size_t)j4 * NHID))[c4];
        f4 v5 = ((const f4*)(h1 + (size_t)j5 * NHID))[c4];
        f4 v6 = ((const f4*)(h1 + (size_t)j6 * NHID))[c4];
        f4 v7 = ((const f4*)(h1 + (size_t)j7 * NHID))[c4];
        float p0, p1, p2, p3, p4, p5, p6, p7;
        e0 += asr; e0 = e0 > 0.f ? e0 : NEG_SLOPE * e0; p0 = __expf(e0);
        e1 += asr; e1 = e1 > 0.f ? e1 : NEG_SLOPE * e1; p1 = __expf(e1);
        e2 += asr; e2 = e2 > 0.f ? e2 : NEG_SLOPE * e2; p2 = __expf(e2);
        e3 += asr; e3 = e3 > 0.f ? e3 : NEG_SLOPE * e3; p3 = __expf(e3);
        e4 += asr; e4 = e4 > 0.f ? e4 : NEG_SLOPE * e4; p4 = __expf(e4);
        e5 += asr; e5 = e5 > 0.f ? e5 : NEG_SLOPE * e5; p5 = __expf(e5);
        e6 += asr; e6 = e6 > 0.f ? e6 : NEG_SLOPE * e6; p6 = __expf(e6);
        e7 += asr; e7 = e7 > 0.f ? e7 : NEG_SLOPE * e7; p7 = __expf(e7);
        ssum += ((p0 + p1) + (p2 + p3)) + ((p4 + p5) + (p6 + p7));
#pragma unroll
        for (int u = 0; u < 4; ++u) {
            acc[u] = fmaf(p0, v0[u], acc[u]); acc[u] = fmaf(p1, v1[u], acc[u]);
            acc[u] = fmaf(p2, v2[u], acc[u]); acc[u] = fmaf(p3, v3[u], acc[u]);
            acc[u] = fmaf(p4, v4[u], acc[u]); acc[u] = fmaf(p5, v5[u], acc[u]);
            acc[u] = fmaf(p6, v6[u], acc[u]); acc[u] = fmaf(p7, v7[u], acc[u]);
        }
    }
    for (; n < cnt; n += 4) {
        int j = s_idx[wid][n];
        float e = asr + ald[j];
        e = e > 0.f ? e : NEG_SLOPE * e;
        float p = __expf(e);
        f4 v = ((const f4*)(h1 + (size_t)j * NHID))[c4];
        ssum += p;
        acc.x = fmaf(p, v.x, acc.x);
        acc.y = fmaf(p, v.y, acc.y);
        acc.z = fmaf(p, v.z, acc.z);
        acc.w = fmaf(p, v.w, acc.w);
    }
    ssum += __shfl_xor(ssum, 16);
    ssum += __shfl_xor(ssum, 32);
    acc.x += __shfl_xor(acc.x, 16); acc.y += __shfl_xor(acc.y, 16);
    acc.z += __shfl_xor(acc.z, 16); acc.w += __shfl_xor(acc.w, 16);
    acc.x += __shfl_xor(acc.x, 32); acc.y += __shfl_xor(acc.y, 32);
    acc.z += __shfl_xor(acc.z, 32); acc.w += __shfl_xor(acc.w, 32);
    float rinv = 1.f / ssum;
    if (kk == 0) {
        f4 o;
#pragma unroll
        for (int j = 0; j < 4; ++j) {
            float t = acc[j] * rinv + b1[c4 * 4 + j];
            o[j] = t > 0.f ? t : expm1f(t);
        }
        ((f4*)s_h[wid])[c4] = o;
    }
    // same-wave LDS handoff: no s_barrier needed (lgkmcnt ordering)

    int c = lane & 15, k = lane >> 4;
    float a2 = 0.f;
#pragma unroll
    for (int f = k * 16; f < k * 16 + 16; ++f)
        a2 = fmaf(s_h[wid][f], W2[f * NCLS + c], a2);
    a2 += __shfl_xor(a2, 16);
    a2 += __shfl_xor(a2, 32);
    if (lane < 16) h2[(size_t)row * NCLS + lane] = a2;
    float ts = a2 * a2s[c], td = a2 * a2d[c];
    ts += __shfl_xor(ts, 1); td += __shfl_xor(td, 1);
    ts += __shfl_xor(ts, 2); td += __shfl_xor(td, 2);
    ts += __shfl_xor(ts, 4); td += __shfl_xor(td, 4);
    ts += __shfl_xor(ts, 8); td += __shfl_xor(td, 8);
    if (lane == 0) { als2[row] = ts; ald2[row] = td; }
}

// K3: SINGLE-PASS layer-2 GAT. lane = (c4 0..3, kk 0..15); merge over d=4..32.
__global__ __launch_bounds__(256) void k3_attn2(
    const float* __restrict__ h2, const float* __restrict__ als2,
    const float* __restrict__ ald2, const float* __restrict__ b2,
    const int* __restrict__ g_cnt, const int* __restrict__ g_nbr,
    float* __restrict__ out) {
    __shared__ int s_idx[4][MAXN];
    int wid = threadIdx.x >> 6, lane = threadIdx.x & 63;
    int row = blockIdx.x * 4 + wid;
    int cnt = g_cnt[row];
    for (int n = lane; n < cnt; n += 64) s_idx[wid][n] = g_nbr[(size_t)row * MAXN + n];

    float asr = als2[row];
    int c4 = lane & 3, kk = lane >> 2;
    f4 acc = {0.f, 0.f, 0.f, 0.f};
    float ssum = 0.f;
#pragma unroll 2
    for (int n = kk; n < cnt; n += 16) {
        int j = s_idx[wid][n];
        float e = asr + ald2[j];
        e = e > 0.f ? e : NEG_SLOPE * e;
        float p = __expf(e);
        f4 v = ((const f4*)(h2 + (size_t)j * NCLS))[c4];
        ssum += p;
        acc.x = fmaf(p, v.x, acc.x);
        acc.y = fmaf(p, v.y, acc.y);
        acc.z = fmaf(p, v.z, acc.z);
        acc.w = fmaf(p, v.w, acc.w);
    }
#pragma unroll
    for (int d = 4; d <= 32; d <<= 1) {
        ssum  += __shfl_xor(ssum, d);
        acc.x += __shfl_xor(acc.x, d); acc.y += __shfl_xor(acc.y, d);
        acc.z += __shfl_xor(acc.z, d); acc.w += __shfl_xor(acc.w, d);
    }
    if (kk == 0) {
        float rinv = 1.f / ssum;
        f4 o;
#pragma unroll
        for (int j = 0; j < 4; ++j) {
            float t = acc[j] * rinv + b2[c4 * 4 + j];
            o[j] = t > 0.f ? t : expm1f(t);
        }
        ((f4*)(out + (size_t)row * NCLS))[c4] = o;
    }
}

extern "C" void kernel_launch(void* const* d_in, const int* in_sizes, int n_in,
                              void* d_out, int out_size, void* d_ws, size_t ws_size,
                              hipStream_t stream) {
    const float* x   = (const float*)d_in[0];
    const float* adj = (const float*)d_in[1];
    const float* W1  = (const float*)d_in[2];
    const float* a1s = (const float*)d_in[3];
    const float* a1d = (const float*)d_in[4];
    const float* b1  = (const float*)d_in[5];
    const float* W2  = (const float*)d_in[6];
    const float* a2s = (const float*)d_in[7];
    const float* a2d = (const float*)d_in[8];
    const float* b2  = (const float*)d_in[9];
    float* out = (float*)d_out;

    char* ws = (char*)d_ws;
    float* h1   = (float*)(ws + 0);          // 2,097,152
    float* h2v  = (float*)(ws + 2097152);    // 524,288
    float* als1 = (float*)(ws + 2621440);
    float* ald1 = (float*)(ws + 2654208);
    float* als2 = (float*)(ws + 2686976);
    float* ald2 = (float*)(ws + 2719744);
    int*   gcnt = (int*)  (ws + 2752512);
    int*   gnbr = (int*)  (ws + 2785280);    // 8,388,608

    dim3 blk(256);
    dim3 grid(NN / 4);
    k1_scan_h1 <<<grid, blk, 0, stream>>>(adj, x, W1, a1s, a1d, h1, als1, ald1, gcnt, gnbr);
    k2_attn1_h2<<<grid, blk, 0, stream>>>(h1, als1, ald1, b1, W2, a2s, a2d, gcnt, gnbr,
                                          h2v, als2, ald2);
    k3_attn2   <<<grid, blk, 0, stream>>>(h2v, als2, ald2, b2, gcnt, gnbr, out);
}